// Round 4
// baseline (166.921 us; speedup 1.0000x reference)
//
#include <hip/hip_runtime.h>
#include <math.h>

typedef float fx4 __attribute__((ext_vector_type(4)));

// DCT-II 8x8 orthonormal matrix constants (match reference _dct_matrix in f32)
#define A0f 0.35355339059327373f
#define B1f 0.49039264020161522f
#define B3f 0.41573480615127262f
#define B5f 0.27778511650980114f
#define B7f 0.09754516100806412f
#define C2f 0.46193976625564337f
#define C6f 0.19134171618254489f

// y[k] = sum_n D[k][n] x[n]
__device__ __forceinline__ void dct1d(const float x[8], float y[8]) {
    float s0 = x[0] + x[7], s1 = x[1] + x[6], s2 = x[2] + x[5], s3 = x[3] + x[4];
    float d0 = x[0] - x[7], d1 = x[1] - x[6], d2 = x[2] - x[5], d3 = x[3] - x[4];
    y[0] = A0f * ((s0 + s3) + (s1 + s2));
    y[4] = A0f * ((s0 + s3) - (s1 + s2));
    y[2] = C2f * s0 + C6f * s1 - C6f * s2 - C2f * s3;
    y[6] = C6f * s0 - C2f * s1 + C2f * s2 - C6f * s3;
    y[1] = B1f * d0 + B3f * d1 + B5f * d2 + B7f * d3;
    y[3] = B3f * d0 - B7f * d1 - B1f * d2 - B5f * d3;
    y[5] = B5f * d0 - B1f * d1 + B7f * d2 + B3f * d3;
    y[7] = B7f * d0 - B5f * d1 + B3f * d2 - B1f * d3;
}

// x[n] = sum_k D[k][n] y[k]
__device__ __forceinline__ void idct1d(const float y[8], float x[8]) {
    float ea = A0f * (y[0] + y[4]);
    float eb = A0f * (y[0] - y[4]);
    float p0 = C2f * y[2] + C6f * y[6];
    float p1 = C6f * y[2] - C2f * y[6];
    float e0 = ea + p0, e1 = eb + p1, e2 = eb - p1, e3 = ea - p0;
    float o0 = B1f * y[1] + B3f * y[3] + B5f * y[5] + B7f * y[7];
    float o1 = B3f * y[1] - B7f * y[3] - B1f * y[5] - B5f * y[7];
    float o2 = B5f * y[1] - B1f * y[3] + B7f * y[5] + B3f * y[7];
    float o3 = B7f * y[1] - B5f * y[3] + B3f * y[5] - B1f * y[7];
    x[0] = e0 + o0; x[7] = e0 - o0;
    x[1] = e1 + o1; x[6] = e1 - o1;
    x[2] = e2 + o2; x[5] = e2 - o2;
    x[3] = e3 + o3; x[4] = e3 - o3;
}

// 8x8 transpose distributed one column (or row) per lane across an aligned
// 8-lane group; 3-stage butterfly via shfl_xor. Involution: cols<->rows.
__device__ __forceinline__ void transpose8(float x[8], int p) {
#pragma unroll
    for (int d = 1; d < 8; d <<= 1) {
        const bool up = (p & d) != 0;
#pragma unroll
        for (int i = 0; i < 8; ++i) {
            if ((i & d) == 0) {
                float send = up ? x[i] : x[i | d];
                float recv = __shfl_xor(send, d, 64);
                if (up) x[i] = recv; else x[i | d] = recv;
            }
        }
    }
}

// DCT -> quant -> dequant -> IDCT of one 8x8 block; thread p owns column p.
template<int STRIDE>
__device__ __forceinline__ void proc_block(float* base, const float* __restrict__ tabp, int p) {
    float qt[8];
#pragma unroll
    for (int k = 0; k < 8; ++k)
        qt[k] = fminf(fmaxf(rintf(tabp[(p << 3) + k]), 1.0f), 32767.0f);
    float v0[8];
#pragma unroll
    for (int i = 0; i < 8; ++i) v0[i] = base[i * STRIDE + p];
    float t[8];
    dct1d(v0, t);            // lane p: column p of D*X
    transpose8(t, p);        // lane p: row p
    float cf[8];
    dct1d(t, cf);            // lane p: row p of coef C = D X D^T
#pragma unroll
    for (int k = 0; k < 8; ++k) cf[k] = rintf(cf[k] / qt[k]) * qt[k];
    float vr[8];
    idct1d(cf, vr);          // lane p: row p of U = C D
    transpose8(vr, p);       // lane p: column p
    float rec[8];
    idct1d(vr, rec);         // lane p: column p of rec = D^T U
#pragma unroll
    for (int i = 0; i < 8; ++i) base[i * STRIDE + p] = rec[i];
}

// One 32x32 pixel tile per WAVE (4 waves / 256-thread block), zero barriers.
// Per tile: 16 Y blocks + 4 Cb + 4 Cr = 24 blocks = 3 rounds x 8 blocks,
// 100% lane utilization. Wave-private LDS; all cross-lane comms in-wave.
__global__ __launch_bounds__(256) void jpeg_fused(
    const float* __restrict__ x, const float* __restrict__ ytab,
    const float* __restrict__ ctab, float* __restrict__ out)
{
    __shared__ float Yt[4][32][36];      // per-wave Y tile (y-128); stride 36: b128-aligned, 2-way banks
    __shared__ float Cs[4][2][16][18];   // per-wave subsampled cb/cr (-128), later reconstructed

    const int tid = threadIdx.x;
    const int w   = tid >> 6;
    const int l   = tid & 63;
    const int T   = blockIdx.x * 4 + w;  // global tile id
    const int b   = T >> 10;             // 1024 tiles per image (32x32 grid)
    const int t_  = T & 1023;
    const int y0  = (t_ >> 5) << 5;
    const int x0  = (t_ & 31) << 5;
    const int imgBase = b * 3145728;

    float (*Ytw)[36]     = Yt[w];
    float (*Csw)[16][18] = Cs[w];

    const int r = l >> 1;                // row 0..31
    const int h = l & 1;                 // column half (16 floats each)
    const int rowOff = imgBase + (y0 + r) * 1024 + x0 + (h << 4);

    // ---------------- staging: load RGB, convert, Y->LDS, chroma pair sums in regs
    float cbs[8], crs[8];
#pragma unroll
    for (int k = 0; k < 4; ++k) {
        const fx4 r4 = *(const fx4*)(x + rowOff + (k << 2));
        const fx4 g4 = *(const fx4*)(x + rowOff + 1048576 + (k << 2));
        const fx4 b4 = *(const fx4*)(x + rowOff + 2097152 + (k << 2));
        fx4 y4;
#pragma unroll
        for (int j = 0; j < 4; ++j) {
            float rr = r4[j] * 255.0f;
            float gg = g4[j] * 255.0f;
            float bb = b4[j] * 255.0f;
            y4[j] = (0.299f * rr + 0.587f * gg + 0.114f * bb) - 128.0f;
            float cb = -0.168736f * rr - 0.331264f * gg + 0.5f * bb;   // cb-128
            float cr = 0.5f * rr - 0.418688f * gg - 0.081312f * bb;    // cr-128
            const int m = (k << 1) + (j >> 1);
            if (j & 1) { cbs[m] += cb; crs[m] += cr; }
            else       { cbs[m]  = cb; crs[m]  = cr; }
        }
        *(fx4*)&Ytw[r][(h << 4) + (k << 2)] = y4;
    }
    // vertical 2x2 completion: rows 2m,2m+1 live in lanes l, l^2
#pragma unroll
    for (int m = 0; m < 8; ++m) {
        float sb = cbs[m] + __shfl_xor(cbs[m], 2, 64);
        float sr = crs[m] + __shfl_xor(crs[m], 2, 64);
        if ((l & 2) == 0) {
            Csw[0][l >> 2][(h << 3) + m] = 0.25f * sb;
            Csw[1][l >> 2][(h << 3) + m] = 0.25f * sr;
        }
    }

    // ---------------- DCT/quant/IDCT: 3 rounds x 8 blocks, all 64 lanes busy
    {
        const int g = l >> 3, p = l & 7;
        // rounds 0,1: Y blocks (block-rows 2*rd + g>>2, block-col g&3)
#pragma unroll
        for (int rd = 0; rd < 2; ++rd) {
            float* base = &Ytw[(((rd << 1) + (g >> 2)) << 3)][(g & 3) << 3];
            proc_block<36>(base, ytab, p);
        }
        // round 2: chroma (ch = g>>2, block-row (g>>1)&1, block-col g&1)
        {
            float* base = &Csw[g >> 2][(g & 2) << 2][(g & 1) << 3];
            proc_block<18>(base, ctab, p);
        }
    }

    // ---------------- upsample chroma, YCbCr->RGB, nontemporal store
    {
        float cbv[8], crv[8];
#pragma unroll
        for (int m = 0; m < 8; ++m) {
            cbv[m] = Csw[0][r >> 1][(h << 3) + m];
            crv[m] = Csw[1][r >> 1][(h << 3) + m];
        }
#pragma unroll
        for (int k = 0; k < 4; ++k) {
            const fx4 y4 = *(const fx4*)&Ytw[r][(h << 4) + (k << 2)];
            fx4 R4, G4, B4;
#pragma unroll
            for (int j = 0; j < 4; ++j) {
                float Yv = y4[j] + 128.0f;
                float cb = cbv[(k << 1) + (j >> 1)];
                float cr = crv[(k << 1) + (j >> 1)];
                R4[j] = (Yv + 1.402f * cr) * (1.0f / 255.0f);
                G4[j] = (Yv - 0.344136f * cb - 0.714136f * cr) * (1.0f / 255.0f);
                B4[j] = (Yv + 1.772f * cb) * (1.0f / 255.0f);
            }
            __builtin_nontemporal_store(R4, (fx4*)(out + rowOff + (k << 2)));
            __builtin_nontemporal_store(G4, (fx4*)(out + rowOff + 1048576 + (k << 2)));
            __builtin_nontemporal_store(B4, (fx4*)(out + rowOff + 2097152 + (k << 2)));
        }
    }
}

extern "C" void kernel_launch(void* const* d_in, const int* in_sizes, int n_in,
                              void* d_out, int out_size, void* d_ws, size_t ws_size,
                              hipStream_t stream) {
    const float* x    = (const float*)d_in[0];
    const float* ytab = (const float*)d_in[1];
    const float* ctab = (const float*)d_in[2];
    float* out = (float*)d_out;
    const int B = in_sizes[0] / 3145728;   // 3*1024*1024 per image
    const int grid = B * 256;              // 1024 tiles/image, 4 tiles(waves)/block
    jpeg_fused<<<grid, 256, 0, stream>>>(x, ytab, ctab, out);
}

// Round 5
// 67.699 us; speedup vs baseline: 2.4656x; 2.4656x over previous
//
#include <hip/hip_runtime.h>
#include <math.h>

typedef float fx4 __attribute__((ext_vector_type(4)));

// DCT-II 8x8 orthonormal matrix constants (match reference _dct_matrix in f32)
#define A0f 0.35355339059327373f
#define B1f 0.49039264020161522f
#define B3f 0.41573480615127262f
#define B5f 0.27778511650980114f
#define B7f 0.09754516100806412f
#define C2f 0.46193976625564337f
#define C6f 0.19134171618254489f

// y[k] = sum_n D[k][n] x[n]
__device__ __forceinline__ void dct1d(const float x[8], float y[8]) {
    float s0 = x[0] + x[7], s1 = x[1] + x[6], s2 = x[2] + x[5], s3 = x[3] + x[4];
    float d0 = x[0] - x[7], d1 = x[1] - x[6], d2 = x[2] - x[5], d3 = x[3] - x[4];
    y[0] = A0f * ((s0 + s3) + (s1 + s2));
    y[4] = A0f * ((s0 + s3) - (s1 + s2));
    y[2] = C2f * s0 + C6f * s1 - C6f * s2 - C2f * s3;
    y[6] = C6f * s0 - C2f * s1 + C2f * s2 - C6f * s3;
    y[1] = B1f * d0 + B3f * d1 + B5f * d2 + B7f * d3;
    y[3] = B3f * d0 - B7f * d1 - B1f * d2 - B5f * d3;
    y[5] = B5f * d0 - B1f * d1 + B7f * d2 + B3f * d3;
    y[7] = B7f * d0 - B5f * d1 + B3f * d2 - B1f * d3;
}

// x[n] = sum_k D[k][n] y[k]
__device__ __forceinline__ void idct1d(const float y[8], float x[8]) {
    float ea = A0f * (y[0] + y[4]);
    float eb = A0f * (y[0] - y[4]);
    float p0 = C2f * y[2] + C6f * y[6];
    float p1 = C6f * y[2] - C2f * y[6];
    float e0 = ea + p0, e1 = eb + p1, e2 = eb - p1, e3 = ea - p0;
    float o0 = B1f * y[1] + B3f * y[3] + B5f * y[5] + B7f * y[7];
    float o1 = B3f * y[1] - B7f * y[3] - B1f * y[5] - B5f * y[7];
    float o2 = B5f * y[1] - B1f * y[3] + B7f * y[5] + B3f * y[7];
    float o3 = B7f * y[1] - B5f * y[3] + B3f * y[5] - B1f * y[7];
    x[0] = e0 + o0; x[7] = e0 - o0;
    x[1] = e1 + o1; x[6] = e1 - o1;
    x[2] = e2 + o2; x[5] = e2 - o2;
    x[3] = e3 + o3; x[4] = e3 - o3;
}

// 8x8 transpose, one column/row per lane across an aligned 8-lane group.
__device__ __forceinline__ void transpose8(float x[8], int p) {
#pragma unroll
    for (int d = 1; d < 8; d <<= 1) {
        const bool up = (p & d) != 0;
#pragma unroll
        for (int i = 0; i < 8; ++i) {
            if ((i & d) == 0) {
                float send = up ? x[i] : x[i | d];
                float recv = __shfl_xor(send, d, 64);
                if (up) x[i] = recv; else x[i | d] = recv;
            }
        }
    }
}

// DCT -> quant -> dequant -> IDCT of one 8x8 block; thread p owns column p.
template<int STRIDE>
__device__ __forceinline__ void proc_block(float* base, const float* __restrict__ tabp, int p) {
    float qt[8];
#pragma unroll
    for (int k = 0; k < 8; ++k)
        qt[k] = fminf(fmaxf(rintf(tabp[(p << 3) + k]), 1.0f), 32767.0f);
    float v0[8];
#pragma unroll
    for (int i = 0; i < 8; ++i) v0[i] = base[i * STRIDE + p];
    float t[8];
    dct1d(v0, t);            // lane p: column p of D*X
    transpose8(t, p);        // lane p: row p
    float cf[8];
    dct1d(t, cf);            // lane p: row p of C = D X D^T
#pragma unroll
    for (int k = 0; k < 8; ++k) cf[k] = rintf(cf[k] / qt[k]) * qt[k];
    float vr[8];
    idct1d(cf, vr);          // lane p: row p of U = C D
    transpose8(vr, p);       // lane p: column p
    float rec[8];
    idct1d(vr, rec);         // lane p: column p of rec = D^T U
#pragma unroll
    for (int i = 0; i < 8; ++i) base[i * STRIDE + p] = rec[i];
}

// One 32x32 pixel tile per WAVE, zero barriers. Lane mapping: row = l>>3 (8 rows
// per instruction), col4 = l&7 (full 128B dense per row) -> no R/W amplification.
__global__ __launch_bounds__(256) void jpeg_fused(
    const float* __restrict__ x, const float* __restrict__ ytab,
    const float* __restrict__ ctab, float* __restrict__ out)
{
    __shared__ float Yt[4][32][36];      // per-wave Y tile (y-128); stride 36 keeps b128 alignment
    __shared__ float Cs[4][2][16][18];   // per-wave subsampled cb/cr (-128), then reconstructed

    const int tid = threadIdx.x;
    const int w   = tid >> 6;
    const int l   = tid & 63;
    const int T   = blockIdx.x * 4 + w;  // global tile id
    const int b   = T >> 10;             // 1024 tiles per image (32x32 grid)
    const int t_  = T & 1023;
    const int y0  = (t_ >> 5) << 5;
    const int x0  = (t_ & 31) << 5;

    float (*Ytw)[36]     = Yt[w];
    float (*Csw)[16][18] = Cs[w];

    const int lr = l >> 3;               // row within an 8-row group
    const int c4 = l & 7;                // float4 column index
    const float* xr = x + (size_t)b * 3145728 + (y0 + lr) * 1024 + x0 + (c4 << 2);
    float* outr     = out + (size_t)b * 3145728 + (y0 + lr) * 1024 + x0 + (c4 << 2);

    // ---------------- staging: load RGB, convert, Y->LDS, chroma 2x2 mean->LDS
#pragma unroll
    for (int k = 0; k < 4; ++k) {
        const int ri = (k << 3) + lr;                 // tile row 0..31
        const fx4 r4 = *(const fx4*)(xr + k * 8192);
        const fx4 g4 = *(const fx4*)(xr + k * 8192 + 1048576);
        const fx4 b4 = *(const fx4*)(xr + k * 8192 + 2097152);
        fx4 y4; float cb[4], cr[4];
#pragma unroll
        for (int j = 0; j < 4; ++j) {
            float rr = r4[j] * 255.0f;
            float gg = g4[j] * 255.0f;
            float bb = b4[j] * 255.0f;
            y4[j]  = (0.299f * rr + 0.587f * gg + 0.114f * bb) - 128.0f;
            cb[j]  = -0.168736f * rr - 0.331264f * gg + 0.5f * bb;     // cb-128
            cr[j]  = 0.5f * rr - 0.418688f * gg - 0.081312f * bb;      // cr-128
        }
        *(fx4*)&Ytw[ri][c4 << 2] = y4;
        float sb0 = cb[0] + cb[1], sb1 = cb[2] + cb[3];
        float sr0 = cr[0] + cr[1], sr1 = cr[2] + cr[3];
        sb0 += __shfl_xor(sb0, 8, 64);                // rows 2m,2m+1 live in lanes l,l^8
        sb1 += __shfl_xor(sb1, 8, 64);
        sr0 += __shfl_xor(sr0, 8, 64);
        sr1 += __shfl_xor(sr1, 8, 64);
        if ((l & 8) == 0) {
            const int rs = (k << 2) + (l >> 4);       // subsampled row 0..15
            Csw[0][rs][(c4 << 1)]     = 0.25f * sb0;
            Csw[0][rs][(c4 << 1) + 1] = 0.25f * sb1;
            Csw[1][rs][(c4 << 1)]     = 0.25f * sr0;
            Csw[1][rs][(c4 << 1) + 1] = 0.25f * sr1;
        }
    }

    // ---------------- DCT/quant/IDCT: 3 rounds x 8 blocks, all 64 lanes busy
    {
        const int g = l >> 3, p = l & 7;
#pragma unroll
        for (int rd = 0; rd < 2; ++rd) {
            float* base = &Ytw[(((rd << 1) + (g >> 2)) << 3)][(g & 3) << 3];
            proc_block<36>(base, ytab, p);
        }
        {
            float* base = &Csw[g >> 2][(g & 2) << 2][(g & 1) << 3];
            proc_block<18>(base, ctab, p);
        }
    }

    // ---------------- upsample chroma, YCbCr->RGB, nontemporal store
#pragma unroll
    for (int k = 0; k < 4; ++k) {
        const int ri = (k << 3) + lr;
        const int rs = ri >> 1;
        const fx4 y4 = *(const fx4*)&Ytw[ri][c4 << 2];
        const float cb0 = Csw[0][rs][(c4 << 1)];
        const float cb1 = Csw[0][rs][(c4 << 1) + 1];
        const float cr0 = Csw[1][rs][(c4 << 1)];
        const float cr1 = Csw[1][rs][(c4 << 1) + 1];
        fx4 R4, G4, B4;
#pragma unroll
        for (int j = 0; j < 4; ++j) {
            float Yv = y4[j] + 128.0f;
            float cb = (j < 2) ? cb0 : cb1;
            float cr = (j < 2) ? cr0 : cr1;
            R4[j] = (Yv + 1.402f * cr) * (1.0f / 255.0f);
            G4[j] = (Yv - 0.344136f * cb - 0.714136f * cr) * (1.0f / 255.0f);
            B4[j] = (Yv + 1.772f * cb) * (1.0f / 255.0f);
        }
        __builtin_nontemporal_store(R4, (fx4*)(outr + k * 8192));
        __builtin_nontemporal_store(G4, (fx4*)(outr + k * 8192 + 1048576));
        __builtin_nontemporal_store(B4, (fx4*)(outr + k * 8192 + 2097152));
    }
}

extern "C" void kernel_launch(void* const* d_in, const int* in_sizes, int n_in,
                              void* d_out, int out_size, void* d_ws, size_t ws_size,
                              hipStream_t stream) {
    const float* x    = (const float*)d_in[0];
    const float* ytab = (const float*)d_in[1];
    const float* ctab = (const float*)d_in[2];
    float* out = (float*)d_out;
    const int B = in_sizes[0] / 3145728;   // 3*1024*1024 per image
    const int grid = B * 256;              // 1024 tiles/image, 4 tiles(waves)/block
    jpeg_fused<<<grid, 256, 0, stream>>>(x, ytab, ctab, out);
}